// Round 13
// baseline (726.807 us; speedup 1.0000x reference)
//
#include <hip/hip_runtime.h>

typedef __attribute__((ext_vector_type(8))) short bf16x8;
typedef __attribute__((ext_vector_type(8))) unsigned short u16x8;
typedef __attribute__((ext_vector_type(4))) float f32x4;
typedef __attribute__((ext_vector_type(2))) unsigned uint2v;
typedef __attribute__((ext_vector_type(4))) unsigned uint4v;

#define DEVINL __device__ __forceinline__

constexpr int TB = 2;        // batch
constexpr int TT = 4096;     // seq len
constexpr int TD = 512;      // model dim
constexpr int TH = 8;        // heads
constexpr int THD = 64;      // head dim
constexpr int TM = TB * TT;  // 8192 flattened rows

// fp32 -> bf16 round-to-nearest-even
DEVINL unsigned short f2b(float f) {
  unsigned u = __builtin_bit_cast(unsigned, f);
  u += 0x7FFFu + ((u >> 16) & 1u);
  return (unsigned short)(u >> 16);
}

// pack 2 f32 -> 2 bf16 in one dword (lo -> low16, hi -> high16), RNE
DEVINL unsigned cvtpk(float lo, float hi) {
  unsigned r;
  asm("v_cvt_pk_bf16_f32 %0, %1, %2" : "=v"(r) : "v"(lo), "v"(hi));
  return r;
}

// barrier that only waits LDS ops (global stores may stay in flight)
DEVINL void lgkm_barrier() {
  asm volatile("s_waitcnt lgkmcnt(0)" ::: "memory");
  __builtin_amdgcn_s_barrier();
  __builtin_amdgcn_sched_barrier(0);
}

// ---------------------------------------------------------------------------
// Fused Q/K/V projection (unchanged from r10).
// ---------------------------------------------------------------------------
__global__ __launch_bounds__(256, 2)
void proj_qkv(const float* __restrict__ Xq, const float* __restrict__ Xk,
              const float* __restrict__ Xv, const float* __restrict__ Wq,
              const float* __restrict__ Wk, const float* __restrict__ Wv,
              unsigned short* __restrict__ qb, unsigned short* __restrict__ kb,
              unsigned short* __restrict__ vt)
{
  constexpr int K = TD, N = TD;
  __shared__ unsigned short As[128][72];
  __shared__ unsigned short Bs[128][72];

  const int z = blockIdx.z;
  const float* X = (z == 0) ? Xq : (z == 1) ? Xk : Xv;
  const float* W = (z == 0) ? Wq : (z == 1) ? Wk : Wv;
  unsigned short* Yb = (z == 0) ? qb : (z == 1) ? kb : vt;
  const bool TR = (z == 2);

  const int t    = threadIdx.x;
  const int lane = t & 63, w = t >> 6;
  const int fr = lane & 15, fq = lane >> 4;
  const int wr = (w >> 1) * 64, wc = (w & 1) * 64;
  const int bm = blockIdx.x * 128, bn = blockIdx.y * 128;
  const int srow = t >> 1;
  const int skh  = (t & 1) * 32;

  f32x4 acc[4][4];
  #pragma unroll
  for (int i = 0; i < 4; ++i)
    #pragma unroll
    for (int j = 0; j < 4; ++j)
      acc[i][j] = f32x4{0.f, 0.f, 0.f, 0.f};

  for (int k0 = 0; k0 < K; k0 += 64) {
    const float* srcA = X + (size_t)(bm + srow) * K + k0 + skh;
    const float* srcB = W + (size_t)(bn + srow) * K + k0 + skh;
    #pragma unroll
    for (int i = 0; i < 4; ++i) {
      float4 a0 = ((const float4*)srcA)[2 * i];
      float4 a1 = ((const float4*)srcA)[2 * i + 1];
      u16x8 oa = {f2b(a0.x), f2b(a0.y), f2b(a0.z), f2b(a0.w),
                  f2b(a1.x), f2b(a1.y), f2b(a1.z), f2b(a1.w)};
      *(u16x8*)&As[srow][skh + i * 8] = oa;
      float4 b0 = ((const float4*)srcB)[2 * i];
      float4 b1 = ((const float4*)srcB)[2 * i + 1];
      u16x8 ob = {f2b(b0.x), f2b(b0.y), f2b(b0.z), f2b(b0.w),
                  f2b(b1.x), f2b(b1.y), f2b(b1.z), f2b(b1.w)};
      *(u16x8*)&Bs[srow][skh + i * 8] = ob;
    }
    __syncthreads();
    #pragma unroll
    for (int kk = 0; kk < 2; ++kk) {
      bf16x8 af[4], bfv[4];
      #pragma unroll
      for (int i = 0; i < 4; ++i)
        af[i] = *(const bf16x8*)&As[wr + i * 16 + fr][kk * 32 + fq * 8];
      #pragma unroll
      for (int j = 0; j < 4; ++j)
        bfv[j] = *(const bf16x8*)&Bs[wc + j * 16 + fr][kk * 32 + fq * 8];
      if (TR) {
        #pragma unroll
        for (int i = 0; i < 4; ++i)
          #pragma unroll
          for (int j = 0; j < 4; ++j)
            acc[i][j] = __builtin_amdgcn_mfma_f32_16x16x32_bf16(bfv[i], af[j], acc[i][j], 0, 0, 0);
      } else {
        #pragma unroll
        for (int i = 0; i < 4; ++i)
          #pragma unroll
          for (int j = 0; j < 4; ++j)
            acc[i][j] = __builtin_amdgcn_mfma_f32_16x16x32_bf16(af[i], bfv[j], acc[i][j], 0, 0, 0);
      }
    }
    __syncthreads();
  }

  if (TR) {
    #pragma unroll
    for (int i = 0; i < 4; ++i)
      #pragma unroll
      for (int j = 0; j < 4; ++j)
        #pragma unroll
        for (int ii = 0; ii < 4; ++ii) {
          const int Nidx = bn + wc + i * 16 + fq * 4 + ii;
          const int Midx = bm + wr + j * 16 + fr;
          const int h = Nidx >> 6, dd = Nidx & (THD - 1);
          const int b = Midx >> 12, tt = Midx & (TT - 1);
          Yb[((size_t)(b * TH + h) * THD + dd) * TT + tt] = f2b(acc[i][j][ii]);
        }
  } else {
    #pragma unroll
    for (int i = 0; i < 4; ++i)
      #pragma unroll
      for (int j = 0; j < 4; ++j)
        #pragma unroll
        for (int ii = 0; ii < 4; ++ii) {
          const int gm = bm + wr + i * 16 + fq * 4 + ii;
          const int gn = bn + wc + j * 16 + fr;
          Yb[(size_t)gm * N + gn] = f2b(acc[i][j][ii]);
        }
  }
}

// ---------------------------------------------------------------------------
// Fused attention v13 = r12 (pass1 PV+lsum, phase-staggered pass2) + the
// final GEMM folded in, overlapped with pass-2 via a device-scope gate:
//  - every block: pass1 -> Z write -> __threadfence -> atomicAdd(counter)
//  - blocks d<512 own one 128x64 out-tile; between pass-2 chunks they check
//    counter==1024 once and run their GEMM tile (LDS overlay; pass-2 staging
//    is re-primed per chunk anyway), hidden under other blocks' stores.
//  - fallback: any un-done gemm runs after pass-2 (counter guaranteed 1024).
// Counter is re-zeroed per replay by an in-graph hipMemsetAsync.
// ---------------------------------------------------------------------------
__global__ __launch_bounds__(256, 4)
void attn_gemm(const unsigned short* __restrict__ Qb,
               const unsigned short* __restrict__ Kb,
               const unsigned short* __restrict__ VTg,
               float* __restrict__ attnO, float* __restrict__ Z,
               const float* __restrict__ Wo, const float* __restrict__ bo,
               float* __restrict__ outO, unsigned* __restrict__ counter)
{
  // pass1: Ks[2][32][72] @0 | VTs[2][64][40] @9216
  // pass2: KsW[4][2][32][72] @0 (36864B)
  // gemm : GAs[128][72] @0 (18432B) | GBs[64][72] @18432 (9216B)
  __shared__ __align__(16) char smem_[36864];
  __shared__ int smflag;
  auto Ks  = (unsigned short (*)[32][72])smem_;
  auto VTs = (unsigned short (*)[64][40])(smem_ + 9216);
  auto KsW = (unsigned short (*)[2][32][72])smem_;
  auto GAs = (unsigned short (*)[72])smem_;
  auto GBs = (unsigned short (*)[72])(smem_ + 18432);

  const int t    = threadIdx.x;
  const int lane = t & 63, w = t >> 6;         // w = 0..3 (q sixteenth)
  const int fr = lane & 15, fq = lane >> 4;

  const int d  = blockIdx.x;                   // 0..1023
  const int bh = 2 * (d & 7) + ((d >> 3) & 1); // 2 bh per XCD
  const int q0 = (d >> 4) * 64;
  const int b  = bh >> 3, h = bh & 7;

  const size_t rowKV  = ((size_t)(b * TT)) * TD + h * THD;
  const size_t vtBase = (size_t)bh * THD * TT;

  const int trK = t >> 3, tcK = (t & 7) * 8;   // K staging 32x64 (block)
  const int trV = t >> 2, tcV = (t & 3) * 8;   // VT staging 64x32 (block)

  auto loadK = [&](int kv0, u16x8& r) {
    r = *(const u16x8*)(Kb + rowKV + (size_t)(kv0 + trK) * TD + tcK);
  };
  auto loadVT = [&](int kv0, u16x8& r) {
    r = *(const u16x8*)(VTg + vtBase + (size_t)trV * TT + kv0 + tcV);
  };
  auto writeK  = [&](int buf, const u16x8& r) { *(u16x8*)&Ks[buf][trK][tcK]  = r; };
  auto writeVT = [&](int buf, const u16x8& r) { *(u16x8*)&VTs[buf][trV][tcV] = r; };

  // Q held in registers (B-operand of swapped QK; row = q = w*16+fr)
  const unsigned short* qsrc = Qb + ((size_t)(b * TT + q0 + w * 16 + fr)) * TD + h * THD;
  bf16x8 aq[2];
  aq[0] = *(const bf16x8*)(qsrc + fq * 8);
  aq[1] = *(const bf16x8*)(qsrc + 32 + fq * 8);

  constexpr int KVB = 32;
  constexpr int NT = TT / KVB;                 // 128 kv tiles
  constexpr float K2 = 0.18033688011112042f;   // (1/8) * log2(e)

  u16x8 kr, vr;
  loadK(0, kr);
  loadVT(0, vr);
  writeK(0, kr);
  writeVT(0, vr);
  lgkm_barrier();

  // ---- pass 1: lsum + unnormalized PV (no global stores) ----
  float lsum = 0.f;
  f32x4 accz[4];
  #pragma unroll
  for (int n = 0; n < 4; ++n) accz[n] = f32x4{0.f, 0.f, 0.f, 0.f};

  for (int j = 0; j < NT; ++j) {
    const int cur = j & 1;
    if (j + 1 < NT) {
      loadK((j + 1) * KVB, kr);
      loadVT((j + 1) * KVB, vr);
    }
    f32x4 sv[2];
    __builtin_amdgcn_s_setprio(1);
    #pragma unroll
    for (int n = 0; n < 2; ++n) {
      f32x4 s = f32x4{0.f, 0.f, 0.f, 0.f};
      #pragma unroll
      for (int kk = 0; kk < 2; ++kk) {
        bf16x8 ak = *(const bf16x8*)&Ks[cur][n * 16 + fr][kk * 32 + fq * 8];
        s = __builtin_amdgcn_mfma_f32_16x16x32_bf16(ak, aq[kk], s, 0, 0, 0);
      }
      sv[n] = s;
    }
    __builtin_amdgcn_s_setprio(0);
    float p[2][4];
    #pragma unroll
    for (int n = 0; n < 2; ++n)
      #pragma unroll
      for (int i = 0; i < 4; ++i) {
        p[n][i] = __builtin_amdgcn_exp2f(sv[n][i] * K2);
        lsum += p[n][i];
      }
    uint4v pav = {cvtpk(p[0][0], p[0][1]), cvtpk(p[0][2], p[0][3]),
                  cvtpk(p[1][0], p[1][1]), cvtpk(p[1][2], p[1][3])};
    bf16x8 ap = __builtin_bit_cast(bf16x8, pav);
    __builtin_amdgcn_s_setprio(1);
    #pragma unroll
    for (int df = 0; df < 4; ++df) {
      uint2v lo = *(const uint2v*)&VTs[cur][df * 16 + fr][fq * 4];
      uint2v hi = *(const uint2v*)&VTs[cur][df * 16 + fr][16 + fq * 4];
      uint4v bvv = {lo[0], lo[1], hi[0], hi[1]};
      accz[df] = __builtin_amdgcn_mfma_f32_16x16x32_bf16(
          ap, __builtin_bit_cast(bf16x8, bvv), accz[df], 0, 0, 0);
    }
    __builtin_amdgcn_s_setprio(0);
    if (j + 1 < NT) {
      writeK(cur ^ 1, kr);
      writeVT(cur ^ 1, vr);
    }
    lgkm_barrier();
  }

  // full row sums (q = w*16+fr lane-local; kv split across fq)
  lsum += __shfl_xor(lsum, 16, 64);
  lsum += __shfl_xor(lsum, 32, 64);

  // Z = accz / lsum; accz row i is q = w*16 + fq*4 + i
  float rls[4];
  #pragma unroll
  for (int i = 0; i < 4; ++i)
    rls[i] = 1.0f / __shfl(lsum, fq * 4 + i, 64);
  const size_t zbase = ((size_t)(b * TT + q0 + w * 16 + fq * 4)) * TD + h * THD + fr;
  #pragma unroll
  for (int df = 0; df < 4; ++df)
    #pragma unroll
    for (int i = 0; i < 4; ++i)
      Z[zbase + (size_t)i * TD + df * 16] = accz[df][i] * rls[i];

  // signal pass-1 completion (Z visible device-wide)
  __threadfence();
  __syncthreads();
  if (t == 0) atomicAdd(counter, 1u);

  const bool isGemmBlock = (d < 512);
  bool gemmDone = !isGemmBlock;

  // GEMM tile for this block: out[128 x 64] at (gm0, gn0)
  const int gm0 = (d >> 3) * 128, gn0 = (d & 7) * 64;
  auto do_gemm = [&]() {
    const int wr = (w >> 1) * 64, wc = (w & 1) * 32;
    const int srow = t >> 1, skh = (t & 1) * 32;   // GAs: 128 rows, 2 thr/row
    const int brow = t >> 2, bkh = (t & 3) * 16;   // GBs: 64 rows, 4 thr/row
    f32x4 gacc[4][2];
    #pragma unroll
    for (int i = 0; i < 4; ++i)
      #pragma unroll
      for (int j = 0; j < 2; ++j)
        gacc[i][j] = f32x4{0.f, 0.f, 0.f, 0.f};
    for (int k0 = 0; k0 < TD; k0 += 64) {
      const float* srcA = Z + (size_t)(gm0 + srow) * TD + k0 + skh;
      #pragma unroll
      for (int i = 0; i < 4; ++i) {
        float4 a0 = ((const float4*)srcA)[2 * i];
        float4 a1 = ((const float4*)srcA)[2 * i + 1];
        u16x8 oa = {f2b(a0.x), f2b(a0.y), f2b(a0.z), f2b(a0.w),
                    f2b(a1.x), f2b(a1.y), f2b(a1.z), f2b(a1.w)};
        *(u16x8*)&GAs[srow][skh + i * 8] = oa;
      }
      const float* srcB = Wo + (size_t)(gn0 + brow) * TD + k0 + bkh;
      #pragma unroll
      for (int i = 0; i < 2; ++i) {
        float4 b0 = ((const float4*)srcB)[2 * i];
        float4 b1 = ((const float4*)srcB)[2 * i + 1];
        u16x8 ob = {f2b(b0.x), f2b(b0.y), f2b(b0.z), f2b(b0.w),
                    f2b(b1.x), f2b(b1.y), f2b(b1.z), f2b(b1.w)};
        *(u16x8*)&GBs[brow][bkh + i * 8] = ob;
      }
      __syncthreads();
      #pragma unroll
      for (int kk = 0; kk < 2; ++kk) {
        bf16x8 af[4], bfv[2];
        #pragma unroll
        for (int i = 0; i < 4; ++i)
          af[i] = *(const bf16x8*)&GAs[wr + i * 16 + fr][kk * 32 + fq * 8];
        #pragma unroll
        for (int j = 0; j < 2; ++j)
          bfv[j] = *(const bf16x8*)&GBs[wc + j * 16 + fr][kk * 32 + fq * 8];
        #pragma unroll
        for (int i = 0; i < 4; ++i)
          #pragma unroll
          for (int j = 0; j < 2; ++j)
            gacc[i][j] = __builtin_amdgcn_mfma_f32_16x16x32_bf16(af[i], bfv[j], gacc[i][j], 0, 0, 0);
      }
      __syncthreads();
    }
    #pragma unroll
    for (int i = 0; i < 4; ++i)
      #pragma unroll
      for (int j = 0; j < 2; ++j)
        #pragma unroll
        for (int ii = 0; ii < 4; ++ii) {
          const int gm = gm0 + wr + i * 16 + fq * 4 + ii;
          const int gn = gn0 + wc + j * 16 + fr;
          outO[(size_t)gm * TD + gn] = gacc[i][j][ii] + bo[gn];
        }
  };

  // ---- pass 2: phase-staggered streamer, chunked, gemm interludes ----
  const float l2i = -__log2f(lsum);
  __syncthreads();                 // retire pass-1 LDS reads before overlay

  const int phase = (37 * d + 32 * w) & (NT - 1);
  const int prow = lane >> 3, pcol = (lane & 7) * 8;
  u16x8 kr4[4];
  auto loadKW = [&](int kvt) {
    #pragma unroll
    for (int i = 0; i < 4; ++i)
      kr4[i] = *(const u16x8*)(Kb + rowKV +
                 (size_t)(kvt * KVB + i * 8 + prow) * TD + pcol);
  };
  auto writeKW = [&](int buf) {
    #pragma unroll
    for (int i = 0; i < 4; ++i)
      *(u16x8*)&KsW[w][buf][i * 8 + prow][pcol] = kr4[i];
  };

  float* arow = attnO + ((size_t)bh * TT + q0 + w * 16 + fr) * TT + fq * 4;

  for (int c = 0; c < 8; ++c) {
    // gemm interlude opportunity (not before chunk 0: give pass-1 tail time)
    if (!gemmDone && c > 0) {
      if (t == 0) smflag = (atomicAdd(counter, 0u) >= 1024u) ? 1 : 0;
      __syncthreads();
      if (smflag) {
        __threadfence();
        do_gemm();
        gemmDone = true;
        __syncthreads();
      }
    }
    // prime this chunk's per-wave pipeline
    const int jj0 = c * 16;
    loadKW((jj0 + phase) & (NT - 1));
    asm volatile("s_waitcnt vmcnt(0)" ::: "memory");
    writeKW(jj0 & 1);
    for (int jj = jj0; jj < jj0 + 16; ++jj) {
      const int cur = jj & 1;
      const int j = (jj + phase) & (NT - 1);
      if (jj + 1 < jj0 + 16) loadKW((jj + 1 + phase) & (NT - 1));
      asm volatile("s_waitcnt lgkmcnt(0)" ::: "memory");
      __builtin_amdgcn_sched_barrier(0);
      f32x4 sv[2];
      __builtin_amdgcn_s_setprio(1);
      #pragma unroll
      for (int n = 0; n < 2; ++n) {
        f32x4 s = f32x4{0.f, 0.f, 0.f, 0.f};
        #pragma unroll
        for (int kk = 0; kk < 2; ++kk) {
          bf16x8 ak = *(const bf16x8*)&KsW[w][cur][n * 16 + fr][kk * 32 + fq * 8];
          s = __builtin_amdgcn_mfma_f32_16x16x32_bf16(ak, aq[kk], s, 0, 0, 0);
        }
        sv[n] = s;
      }
      __builtin_amdgcn_s_setprio(0);
      #pragma unroll
      for (int n = 0; n < 2; ++n) {
        f32x4 pv4 = {__builtin_amdgcn_exp2f(fmaf(sv[n][0], K2, l2i)),
                     __builtin_amdgcn_exp2f(fmaf(sv[n][1], K2, l2i)),
                     __builtin_amdgcn_exp2f(fmaf(sv[n][2], K2, l2i)),
                     __builtin_amdgcn_exp2f(fmaf(sv[n][3], K2, l2i))};
        *(f32x4*)(arow + j * KVB + n * 16) = pv4;
      }
      if (jj + 1 < jj0 + 16) writeKW(cur ^ 1);
    }
  }

  // fallback: guaranteed-ready gemm after pass-2
  if (!gemmDone) {
    if (t == 0) {
      while (atomicAdd(counter, 0u) < 1024u) __builtin_amdgcn_s_sleep(8);
      smflag = 1;
    }
    __syncthreads();
    __threadfence();
    do_gemm();
  }
}

// ---------------------------------------------------------------------------
extern "C" void kernel_launch(void* const* d_in, const int* in_sizes, int n_in,
                              void* d_out, int out_size, void* d_ws, size_t ws_size,
                              hipStream_t stream) {
  const float* queries = (const float*)d_in[0];
  const float* keys    = (const float*)d_in[1];
  const float* values  = (const float*)d_in[2];
  const float* Wq = (const float*)d_in[3];
  const float* Wk = (const float*)d_in[4];
  const float* Wv = (const float*)d_in[5];
  const float* Wo = (const float*)d_in[6];
  const float* bo = (const float*)d_in[7];

  float* out  = (float*)d_out;                       // [2,4096,512]
  float* attn = out + (size_t)TM * TD;               // [2,8,4096,4096]

  unsigned short* qb = (unsigned short*)d_ws;
  unsigned short* kb = qb + (size_t)TM * TD;
  unsigned short* vt = kb + (size_t)TM * TD;
  float*          zf = (float*)(vt + (size_t)TM * TD);
  unsigned*       counter = (unsigned*)(zf + (size_t)TM * TD);

  proj_qkv<<<dim3(TM / 128, TD / 128, 3), 256, 0, stream>>>(
      queries, keys, values, Wq, Wk, Wv, qb, kb, vt);

  hipMemsetAsync(counter, 0, sizeof(unsigned), stream);

  attn_gemm<<<dim3(1024), 256, 0, stream>>>(qb, kb, vt, attn, zf,
                                            Wo, bo, out, counter);
}

// Round 14
// 488.560 us; speedup vs baseline: 1.4877x; 1.4877x over previous
//
#include <hip/hip_runtime.h>

typedef __attribute__((ext_vector_type(8))) short bf16x8;
typedef __attribute__((ext_vector_type(8))) unsigned short u16x8;
typedef __attribute__((ext_vector_type(4))) float f32x4;
typedef __attribute__((ext_vector_type(2))) unsigned uint2v;
typedef __attribute__((ext_vector_type(4))) unsigned uint4v;

#define DEVINL __device__ __forceinline__

constexpr int TB = 2;        // batch
constexpr int TT = 4096;     // seq len
constexpr int TD = 512;      // model dim
constexpr int TH = 8;        // heads
constexpr int THD = 64;      // head dim
constexpr int TM = TB * TT;  // 8192 flattened rows

// fp32 -> bf16 round-to-nearest-even
DEVINL unsigned short f2b(float f) {
  unsigned u = __builtin_bit_cast(unsigned, f);
  u += 0x7FFFu + ((u >> 16) & 1u);
  return (unsigned short)(u >> 16);
}

// pack 2 f32 -> 2 bf16 in one dword
DEVINL unsigned cvtpk(float lo, float hi) {
  unsigned r;
  asm("v_cvt_pk_bf16_f32 %0, %1, %2" : "=v"(r) : "v"(lo), "v"(hi));
  return r;
}

// barrier that only waits LDS ops (global stores may stay in flight)
DEVINL void lgkm_barrier() {
  asm volatile("s_waitcnt lgkmcnt(0)" ::: "memory");
  __builtin_amdgcn_s_barrier();
  __builtin_amdgcn_sched_barrier(0);
}

// ---------------------------------------------------------------------------
// Fused Q/K/V projection (unchanged).
// ---------------------------------------------------------------------------
__global__ __launch_bounds__(256, 2)
void proj_qkv(const float* __restrict__ Xq, const float* __restrict__ Xk,
              const float* __restrict__ Xv, const float* __restrict__ Wq,
              const float* __restrict__ Wk, const float* __restrict__ Wv,
              unsigned short* __restrict__ qb, unsigned short* __restrict__ kb,
              unsigned short* __restrict__ vt)
{
  constexpr int K = TD, N = TD;
  __shared__ unsigned short As[128][72];
  __shared__ unsigned short Bs[128][72];

  const int z = blockIdx.z;
  const float* X = (z == 0) ? Xq : (z == 1) ? Xk : Xv;
  const float* W = (z == 0) ? Wq : (z == 1) ? Wk : Wv;
  unsigned short* Yb = (z == 0) ? qb : (z == 1) ? kb : vt;
  const bool TR = (z == 2);

  const int t    = threadIdx.x;
  const int lane = t & 63, w = t >> 6;
  const int fr = lane & 15, fq = lane >> 4;
  const int wr = (w >> 1) * 64, wc = (w & 1) * 64;
  const int bm = blockIdx.x * 128, bn = blockIdx.y * 128;
  const int srow = t >> 1;
  const int skh  = (t & 1) * 32;

  f32x4 acc[4][4];
  #pragma unroll
  for (int i = 0; i < 4; ++i)
    #pragma unroll
    for (int j = 0; j < 4; ++j)
      acc[i][j] = f32x4{0.f, 0.f, 0.f, 0.f};

  for (int k0 = 0; k0 < K; k0 += 64) {
    const float* srcA = X + (size_t)(bm + srow) * K + k0 + skh;
    const float* srcB = W + (size_t)(bn + srow) * K + k0 + skh;
    #pragma unroll
    for (int i = 0; i < 4; ++i) {
      float4 a0 = ((const float4*)srcA)[2 * i];
      float4 a1 = ((const float4*)srcA)[2 * i + 1];
      u16x8 oa = {f2b(a0.x), f2b(a0.y), f2b(a0.z), f2b(a0.w),
                  f2b(a1.x), f2b(a1.y), f2b(a1.z), f2b(a1.w)};
      *(u16x8*)&As[srow][skh + i * 8] = oa;
      float4 b0 = ((const float4*)srcB)[2 * i];
      float4 b1 = ((const float4*)srcB)[2 * i + 1];
      u16x8 ob = {f2b(b0.x), f2b(b0.y), f2b(b0.z), f2b(b0.w),
                  f2b(b1.x), f2b(b1.y), f2b(b1.z), f2b(b1.w)};
      *(u16x8*)&Bs[srow][skh + i * 8] = ob;
    }
    __syncthreads();
    #pragma unroll
    for (int kk = 0; kk < 2; ++kk) {
      bf16x8 af[4], bfv[4];
      #pragma unroll
      for (int i = 0; i < 4; ++i)
        af[i] = *(const bf16x8*)&As[wr + i * 16 + fr][kk * 32 + fq * 8];
      #pragma unroll
      for (int j = 0; j < 4; ++j)
        bfv[j] = *(const bf16x8*)&Bs[wc + j * 16 + fr][kk * 32 + fq * 8];
      if (TR) {
        #pragma unroll
        for (int i = 0; i < 4; ++i)
          #pragma unroll
          for (int j = 0; j < 4; ++j)
            acc[i][j] = __builtin_amdgcn_mfma_f32_16x16x32_bf16(bfv[i], af[j], acc[i][j], 0, 0, 0);
      } else {
        #pragma unroll
        for (int i = 0; i < 4; ++i)
          #pragma unroll
          for (int j = 0; j < 4; ++j)
            acc[i][j] = __builtin_amdgcn_mfma_f32_16x16x32_bf16(af[i], bfv[j], acc[i][j], 0, 0, 0);
      }
    }
    __syncthreads();
  }

  if (TR) {
    #pragma unroll
    for (int i = 0; i < 4; ++i)
      #pragma unroll
      for (int j = 0; j < 4; ++j)
        #pragma unroll
        for (int ii = 0; ii < 4; ++ii) {
          const int Nidx = bn + wc + i * 16 + fq * 4 + ii;
          const int Midx = bm + wr + j * 16 + fr;
          const int h = Nidx >> 6, dd = Nidx & (THD - 1);
          const int b = Midx >> 12, tt = Midx & (TT - 1);
          Yb[((size_t)(b * TH + h) * THD + dd) * TT + tt] = f2b(acc[i][j][ii]);
        }
  } else {
    #pragma unroll
    for (int i = 0; i < 4; ++i)
      #pragma unroll
      for (int j = 0; j < 4; ++j)
        #pragma unroll
        for (int ii = 0; ii < 4; ++ii) {
          const int gm = bm + wr + i * 16 + fq * 4 + ii;
          const int gn = bn + wc + j * 16 + fr;
          Yb[(size_t)gm * N + gn] = f2b(acc[i][j][ii]);
        }
  }
}

// ---------------------------------------------------------------------------
// Final GEMM: out = zf @ Wo^T + bo (fp32 out).  (standalone again)
// ---------------------------------------------------------------------------
__global__ __launch_bounds__(256, 2)
void gemm_final(const float* __restrict__ X, const float* __restrict__ W,
                float* __restrict__ Yf, const float* __restrict__ bias)
{
  constexpr int K = TD, N = TD;
  __shared__ unsigned short As[128][72];
  __shared__ unsigned short Bs[128][72];

  const int t    = threadIdx.x;
  const int lane = t & 63, w = t >> 6;
  const int fr = lane & 15, fq = lane >> 4;
  const int wr = (w >> 1) * 64, wc = (w & 1) * 64;
  const int bm = blockIdx.x * 128, bn = blockIdx.y * 128;
  const int srow = t >> 1;
  const int skh  = (t & 1) * 32;

  f32x4 acc[4][4];
  #pragma unroll
  for (int i = 0; i < 4; ++i)
    #pragma unroll
    for (int j = 0; j < 4; ++j)
      acc[i][j] = f32x4{0.f, 0.f, 0.f, 0.f};

  for (int k0 = 0; k0 < K; k0 += 64) {
    const float* srcA = X + (size_t)(bm + srow) * K + k0 + skh;
    const float* srcB = W + (size_t)(bn + srow) * K + k0 + skh;
    #pragma unroll
    for (int i = 0; i < 4; ++i) {
      float4 a0 = ((const float4*)srcA)[2 * i];
      float4 a1 = ((const float4*)srcA)[2 * i + 1];
      u16x8 oa = {f2b(a0.x), f2b(a0.y), f2b(a0.z), f2b(a0.w),
                  f2b(a1.x), f2b(a1.y), f2b(a1.z), f2b(a1.w)};
      *(u16x8*)&As[srow][skh + i * 8] = oa;
      float4 b0 = ((const float4*)srcB)[2 * i];
      float4 b1 = ((const float4*)srcB)[2 * i + 1];
      u16x8 ob = {f2b(b0.x), f2b(b0.y), f2b(b0.z), f2b(b0.w),
                  f2b(b1.x), f2b(b1.y), f2b(b1.z), f2b(b1.w)};
      *(u16x8*)&Bs[srow][skh + i * 8] = ob;
    }
    __syncthreads();
    #pragma unroll
    for (int kk = 0; kk < 2; ++kk) {
      bf16x8 af[4], bfv[4];
      #pragma unroll
      for (int i = 0; i < 4; ++i)
        af[i] = *(const bf16x8*)&As[wr + i * 16 + fr][kk * 32 + fq * 8];
      #pragma unroll
      for (int j = 0; j < 4; ++j)
        bfv[j] = *(const bf16x8*)&Bs[wc + j * 16 + fr][kk * 32 + fq * 8];
      #pragma unroll
      for (int i = 0; i < 4; ++i)
        #pragma unroll
        for (int j = 0; j < 4; ++j)
          acc[i][j] = __builtin_amdgcn_mfma_f32_16x16x32_bf16(af[i], bfv[j], acc[i][j], 0, 0, 0);
    }
    __syncthreads();
  }

  #pragma unroll
  for (int i = 0; i < 4; ++i)
    #pragma unroll
    for (int j = 0; j < 4; ++j)
      #pragma unroll
      for (int ii = 0; ii < 4; ++ii) {
        const int gm = bm + wr + i * 16 + fq * 4 + ii;
        const int gn = bn + wc + j * 16 + fr;
        Yf[(size_t)gm * N + gn] = acc[i][j][ii] + bias[gn];
      }
}

// ---------------------------------------------------------------------------
// PASS 1 (own kernel): lsum + unnormalized PV -> Z (normalized) + l2i to ws.
// Distance-2 staging pipeline: loads for tile j+2 issue at iter j, ds_write
// of tile j+1 uses regs loaded one full iteration earlier (vmcnt slack).
// ---------------------------------------------------------------------------
__global__ __launch_bounds__(256, 4)
void attn_pass1(const unsigned short* __restrict__ Qb,
                const unsigned short* __restrict__ Kb,
                const unsigned short* __restrict__ VTg,
                float* __restrict__ Z, float* __restrict__ l2iW)
{
  __shared__ unsigned short Ks[2][32][72];     // 9.0 KB
  __shared__ unsigned short VTs[2][64][40];    // 10.0 KB

  const int t    = threadIdx.x;
  const int lane = t & 63, w = t >> 6;
  const int fr = lane & 15, fq = lane >> 4;

  const int d  = blockIdx.x;                   // 0..1023
  const int bh = 2 * (d & 7) + ((d >> 3) & 1); // 2 bh per XCD
  const int q0 = (d >> 4) * 64;
  const int b  = bh >> 3, h = bh & 7;

  const size_t rowKV  = ((size_t)(b * TT)) * TD + h * THD;
  const size_t vtBase = (size_t)bh * THD * TT;

  const int trK = t >> 3, tcK = (t & 7) * 8;
  const int trV = t >> 2, tcV = (t & 3) * 8;

  auto loadK = [&](int kv0, u16x8& r) {
    r = *(const u16x8*)(Kb + rowKV + (size_t)(kv0 + trK) * TD + tcK);
  };
  auto loadVT = [&](int kv0, u16x8& r) {
    r = *(const u16x8*)(VTg + vtBase + (size_t)trV * TT + kv0 + tcV);
  };
  auto writeK  = [&](int buf, const u16x8& r) { *(u16x8*)&Ks[buf][trK][tcK]  = r; };
  auto writeVT = [&](int buf, const u16x8& r) { *(u16x8*)&VTs[buf][trV][tcV] = r; };

  const unsigned short* qsrc = Qb + ((size_t)(b * TT + q0 + w * 16 + fr)) * TD + h * THD;
  bf16x8 aq[2];
  aq[0] = *(const bf16x8*)(qsrc + fq * 8);
  aq[1] = *(const bf16x8*)(qsrc + 32 + fq * 8);

  constexpr int KVB = 32;
  constexpr int NT = TT / KVB;                 // 128
  constexpr float K2 = 0.18033688011112042f;   // (1/8) * log2(e)

  // staging register sets: sX loaded at iter j lands in buf at iter j+1
  u16x8 kA, vA, kB, vB;
  {
    u16x8 k0, v0;
    loadK(0, k0); loadVT(0, v0);
    writeK(0, k0); writeVT(0, v0);             // vmcnt(0) once in prologue
    loadK(KVB, kB); loadVT(KVB, vB);           // tile 1 -> set B
    lgkm_barrier();
  }

  float lsum = 0.f;
  f32x4 accz[4];
  #pragma unroll
  for (int n = 0; n < 4; ++n) accz[n] = f32x4{0.f, 0.f, 0.f, 0.f};

  for (int jp = 0; jp < NT / 2; ++jp) {
    #pragma unroll
    for (int half = 0; half < 2; ++half) {
      const int j = jp * 2 + half;
      const int cur = j & 1;
      // load tile j+2 into the set NOT pending-write (even->A, odd->B)
      if (j + 2 < NT) {
        if (half == 0) { loadK((j + 2) * KVB, kA); loadVT((j + 2) * KVB, vA); }
        else           { loadK((j + 2) * KVB, kB); loadVT((j + 2) * KVB, vB); }
      }
      // compute tile j from buf[cur]
      f32x4 sv[2];
      __builtin_amdgcn_s_setprio(1);
      #pragma unroll
      for (int n = 0; n < 2; ++n) {
        f32x4 s = f32x4{0.f, 0.f, 0.f, 0.f};
        #pragma unroll
        for (int kk = 0; kk < 2; ++kk) {
          bf16x8 ak = *(const bf16x8*)&Ks[cur][n * 16 + fr][kk * 32 + fq * 8];
          s = __builtin_amdgcn_mfma_f32_16x16x32_bf16(ak, aq[kk], s, 0, 0, 0);
        }
        sv[n] = s;
      }
      __builtin_amdgcn_s_setprio(0);
      float p[2][4];
      #pragma unroll
      for (int n = 0; n < 2; ++n)
        #pragma unroll
        for (int i = 0; i < 4; ++i) {
          p[n][i] = __builtin_amdgcn_exp2f(sv[n][i] * K2);
          lsum += p[n][i];
        }
      uint4v pav = {cvtpk(p[0][0], p[0][1]), cvtpk(p[0][2], p[0][3]),
                    cvtpk(p[1][0], p[1][1]), cvtpk(p[1][2], p[1][3])};
      bf16x8 ap = __builtin_bit_cast(bf16x8, pav);
      __builtin_amdgcn_s_setprio(1);
      #pragma unroll
      for (int df = 0; df < 4; ++df) {
        uint2v lo = *(const uint2v*)&VTs[cur][df * 16 + fr][fq * 4];
        uint2v hi = *(const uint2v*)&VTs[cur][df * 16 + fr][16 + fq * 4];
        uint4v bvv = {lo[0], lo[1], hi[0], hi[1]};
        accz[df] = __builtin_amdgcn_mfma_f32_16x16x32_bf16(
            ap, __builtin_bit_cast(bf16x8, bvv), accz[df], 0, 0, 0);
      }
      __builtin_amdgcn_s_setprio(0);
      // stage tile j+1 (regs loaded at iter j-1: even writes B, odd writes A)
      if (j + 1 < NT) {
        if (half == 0) { writeK(cur ^ 1, kB); writeVT(cur ^ 1, vB); }
        else           { writeK(cur ^ 1, kA); writeVT(cur ^ 1, vA); }
      }
      lgkm_barrier();
    }
  }

  // full row sums (q = w*16+fr lane-local; kv split across fq)
  lsum += __shfl_xor(lsum, 16, 64);
  lsum += __shfl_xor(lsum, 32, 64);

  // l2i to ws (one lane per q)
  if (fq == 0)
    l2iW[(size_t)bh * TT + q0 + w * 16 + fr] = -__log2f(lsum);

  // Z = accz / lsum; accz row i is q = w*16 + fq*4 + i
  float rls[4];
  #pragma unroll
  for (int i = 0; i < 4; ++i)
    rls[i] = 1.0f / __shfl(lsum, fq * 4 + i, 64);
  const size_t zbase = ((size_t)(b * TT + q0 + w * 16 + fq * 4)) * TD + h * THD + fr;
  #pragma unroll
  for (int df = 0; df < 4; ++df)
    #pragma unroll
    for (int i = 0; i < 4; ++i)
      Z[zbase + (size_t)i * TD + df * 16] = accz[df][i] * rls[i];
}

// ---------------------------------------------------------------------------
// PASS 2 (own kernel): phase-staggered store streamer, per-wave staging,
// barrier-free, distance-2 pipeline (named sets sA/sB, unrolled pair loop).
// ---------------------------------------------------------------------------
__global__ __launch_bounds__(256, 4)
void attn_pass2(const unsigned short* __restrict__ Qb,
                const unsigned short* __restrict__ Kb,
                const float* __restrict__ l2iW,
                float* __restrict__ attnO)
{
  __shared__ unsigned short KsW[4][2][32][72];   // 36.9 KB per-wave dbuf

  const int t    = threadIdx.x;
  const int lane = t & 63, w = t >> 6;
  const int fr = lane & 15, fq = lane >> 4;

  const int d  = blockIdx.x;
  const int bh = 2 * (d & 7) + ((d >> 3) & 1);
  const int q0 = (d >> 4) * 64;
  const int b  = bh >> 3, h = bh & 7;

  const size_t rowKV = ((size_t)(b * TT)) * TD + h * THD;

  const unsigned short* qsrc = Qb + ((size_t)(b * TT + q0 + w * 16 + fr)) * TD + h * THD;
  bf16x8 aq[2];
  aq[0] = *(const bf16x8*)(qsrc + fq * 8);
  aq[1] = *(const bf16x8*)(qsrc + 32 + fq * 8);

  const float l2i = l2iW[(size_t)bh * TT + q0 + w * 16 + fr];

  constexpr int KVB = 32;
  constexpr int NT = TT / KVB;                  // 128
  constexpr float K2 = 0.18033688011112042f;

  const int phase = (37 * d + 32 * w) & (NT - 1);
  const int prow = lane >> 3, pcol = (lane & 7) * 8;

  u16x8 sA[4], sB[4];
  auto loadKW = [&](int kvt, u16x8* s) {
    #pragma unroll
    for (int i = 0; i < 4; ++i)
      s[i] = *(const u16x8*)(Kb + rowKV +
               (size_t)(kvt * KVB + i * 8 + prow) * TD + pcol);
  };
  auto writeKW = [&](int buf, const u16x8* s) {
    #pragma unroll
    for (int i = 0; i < 4; ++i)
      *(u16x8*)&KsW[w][buf][i * 8 + prow][pcol] = s[i];
  };
  auto PH = [&](int jj) { return (jj + phase) & (NT - 1); };

  float* arow = attnO + ((size_t)bh * TT + q0 + w * 16 + fr) * TT + fq * 4;

#define P2_COMPUTE(JJ, BUF)                                                    \
  {                                                                            \
    const int j = PH(JJ);                                                      \
    f32x4 sv[2];                                                               \
    __builtin_amdgcn_s_setprio(1);                                             \
    _Pragma("unroll")                                                          \
    for (int n = 0; n < 2; ++n) {                                              \
      f32x4 s = f32x4{0.f, 0.f, 0.f, 0.f};                                     \
      _Pragma("unroll")                                                        \
      for (int kk = 0; kk < 2; ++kk) {                                         \
        bf16x8 ak = *(const bf16x8*)&KsW[w][(BUF)][n * 16 + fr][kk * 32 + fq * 8]; \
        s = __builtin_amdgcn_mfma_f32_16x16x32_bf16(ak, aq[kk], s, 0, 0, 0);   \
      }                                                                        \
      sv[n] = s;                                                               \
    }                                                                          \
    __builtin_amdgcn_s_setprio(0);                                             \
    _Pragma("unroll")                                                          \
    for (int n = 0; n < 2; ++n) {                                              \
      f32x4 pv4 = {__builtin_amdgcn_exp2f(fmaf(sv[n][0], K2, l2i)),            \
                   __builtin_amdgcn_exp2f(fmaf(sv[n][1], K2, l2i)),            \
                   __builtin_amdgcn_exp2f(fmaf(sv[n][2], K2, l2i)),            \
                   __builtin_amdgcn_exp2f(fmaf(sv[n][3], K2, l2i))};           \
      *(f32x4*)(arow + j * KVB + n * 16) = pv4;                                \
    }                                                                          \
  }

  // prologue: tile0 -> buf0; tile1 -> sB
  loadKW(PH(0), sA);
  writeKW(0, sA);              // compiler inserts the one prologue vmcnt
  loadKW(PH(1), sB);

  for (int jp = 0; jp < NT / 2; ++jp) {
    const int jj0 = 2 * jp;
    // even: read buf0 (tile jj0); load jj0+2 -> sA; write buf1 from sB (jj0+1)
    if (jj0 + 2 < NT) loadKW(PH(jj0 + 2), sA);
    P2_COMPUTE(jj0, 0)
    writeKW(1, sB);
    // odd: read buf1 (tile jj0+1); load jj0+3 -> sB; write buf0 from sA
    if (jj0 + 3 < NT) loadKW(PH(jj0 + 3), sB);
    P2_COMPUTE(jj0 + 1, 1)
    if (jj0 + 2 < NT) writeKW(0, sA);
  }
#undef P2_COMPUTE
}

// ---------------------------------------------------------------------------
extern "C" void kernel_launch(void* const* d_in, const int* in_sizes, int n_in,
                              void* d_out, int out_size, void* d_ws, size_t ws_size,
                              hipStream_t stream) {
  const float* queries = (const float*)d_in[0];
  const float* keys    = (const float*)d_in[1];
  const float* values  = (const float*)d_in[2];
  const float* Wq = (const float*)d_in[3];
  const float* Wk = (const float*)d_in[4];
  const float* Wv = (const float*)d_in[5];
  const float* Wo = (const float*)d_in[6];
  const float* bo = (const float*)d_in[7];

  float* out  = (float*)d_out;                       // [2,4096,512]
  float* attn = out + (size_t)TM * TD;               // [2,8,4096,4096]

  unsigned short* qb = (unsigned short*)d_ws;
  unsigned short* kb = qb + (size_t)TM * TD;
  unsigned short* vt = kb + (size_t)TM * TD;
  float*          zf = (float*)(vt + (size_t)TM * TD);
  float*          l2iW = zf + (size_t)TM * TD;       // [16][4096]

  proj_qkv<<<dim3(TM / 128, TD / 128, 3), 256, 0, stream>>>(
      queries, keys, values, Wq, Wk, Wv, qb, kb, vt);

  attn_pass1<<<dim3(1024), 256, 0, stream>>>(qb, kb, vt, zf, l2iW);

  attn_pass2<<<dim3(1024), 256, 0, stream>>>(qb, kb, l2iW, attn);

  gemm_final<<<dim3(TM / 128, TD / 128), 256, 0, stream>>>(zf, Wo, out, bo);
}